// Round 8
// baseline (63.253 us; speedup 1.0000x reference)
//
#include <hip/hip_runtime.h>

// Bilinear flow warp, LDS row-tile v5: taller tiles to cut halo redundancy.
// images [32,3,512,512] f32, flows [32,2,512,512] f32 (ch0=dy, ch1=dx).
//
// R7 post-mortem: dbuf neutral, and R6 (4 blk/CU) == R7 (2 blk/CU) in both
// perf and measured occupancy (~40%) -> neither stage latency nor TLP binds.
// Pipe sums leave one candidate at the 106K cy/CU budget: the L3/fabric read
// stream (flows 67MB + images 201MB incl 2.0x halo redundancy). This round:
// TH 8->16 with 1024-thread blocks (tile 512x16, LROWS=24, HALO=4) cuts
// redundancy to 1.5x -> total reads -19%. Same 8px/thread state, same
// global_load_lds staging contract, single buffer (dbuf proven neutral).
// LDS 48KB -> 2 blocks/CU = 32 waves theoretical.

constexpr int C = 3, H = 512, W = 512, HW = H * W;
constexpr int TH = 16, HALO = 4;
constexpr int LROWS = TH + 2 * HALO;      // 24 staged rows
constexpr int LWP   = W;                  // 512: stride == 0 mod 32 banks
constexpr int TILES = 32 * (H / TH);      // 1024 blocks, %8 == 0

__global__ __launch_bounds__(1024, 8) void warp_bilinear_rows(
    const float* __restrict__ images,
    const float* __restrict__ flows,
    float* __restrict__ out)
{
    __shared__ float tile[LROWS * LWP];   // 49,152 B

    // XCD-contiguous: XCD r owns tiles [r*128,(r+1)*128) = 4 whole batches.
    int bid = blockIdx.x;
    int tile_id = (bid & 7) * (TILES / 8) + (bid >> 3);
    int b   = tile_id >> 5;               // 32 strips per batch
    int ty0 = (tile_id & 31) * TH;

    int tid  = threadIdx.x;               // 0..1023
    int xg   = tid & 511;                 // my column
    int half = tid >> 9;                  // 0/1: which 8-row half I own
    int yb   = ty0 + half * 8;            // my first output row

    // ---- flow load + channel-independent gather state (8 px/thread) ----
    const float* flow_y = flows + (size_t)b * 2 * HW + yb * W + xg;
    const float* flow_x = flow_y + HW;

    float dxv[8], dyv[8];
    int   li[8];
    unsigned okm = 0;
#pragma unroll
    for (int k = 0; k < 8; ++k) {
        float fy = flow_y[k * W];
        float fx = flow_x[k * W];
        float sx = fminf(fmaxf((float)xg + fx, 0.0f), (float)(W - 1));
        float sy = fminf(fmaxf((float)(yb + k) + fy, 0.0f), (float)(H - 1));
        int x0 = min((int)sx, W - 2);     // sx >= 0 so (int) == floor
        int y0 = min((int)sy, H - 2);
        dxv[k] = sx - (float)x0;
        dyv[k] = sy - (float)y0;
        int ly0 = y0 - (ty0 - HALO);
        bool ok = (ly0 >= 0) & (ly0 <= LROWS - 2);
        okm |= (unsigned)ok << k;
        li[k] = ok ? (ly0 * LWP + x0)     // LDS offset (x needs no halo)
                   : (y0 * W + x0);       // global fallback offset
    }
    bool fast = __all(okm == 0xFFu);

    // staging addresses (channel-invariant): wave-uniform row + lane*16B
    //   iter it covers rows it*8 + (tid>>7); cols (tid&127)*4 .. +3
    int srow[LROWS / 8];
    int scol = (tid & 127) * 4;
#pragma unroll
    for (int it = 0; it < LROWS / 8; ++it) {      // 3 iters, 8 rows each
        int r = it * 8 + (tid >> 7);
        srow[it] = min(max(ty0 - HALO + r, 0), H - 1);
    }

    for (int c = 0; c < C; ++c) {
        const float* gimg = images + ((size_t)b * C + c) * HW;
        __syncthreads();                  // previous channel's reads done
#pragma unroll
        for (int it = 0; it < LROWS / 8; ++it) {
            int r = it * 8 + (tid >> 7);
            __builtin_amdgcn_global_load_lds(
                (const __attribute__((address_space(1))) void*)(gimg + srow[it] * W + scol),
                (__attribute__((address_space(3))) void*)(&tile[r * LWP + scol]),
                16, 0, 0);
        }
        __syncthreads();                  // drains vmcnt -> tile ready

        float* outc = out + ((size_t)b * C + c) * HW + yb * W + xg;
        if (fast) {
#pragma unroll
            for (int k = 0; k < 8; ++k) {
                float dx = dxv[k], dy = dyv[k];
                float wa = (1.0f - dx) * (1.0f - dy);
                float wb = (1.0f - dx) * dy;
                float wc = dx * (1.0f - dy);
                float wd = dx * dy;
                int t = li[k];
                float Ia = tile[t];        float Ic = tile[t + 1];
                float Ib = tile[t + LWP];  float Id = tile[t + LWP + 1];
                __builtin_nontemporal_store(
                    wa * Ia + wb * Ib + wc * Ic + wd * Id, outc + k * W);
            }
        } else {                           // rare: |dy| > ~4 near strip edge
#pragma unroll
            for (int k = 0; k < 8; ++k) {
                float dx = dxv[k], dy = dyv[k];
                float wa = (1.0f - dx) * (1.0f - dy);
                float wb = (1.0f - dx) * dy;
                float wc = dx * (1.0f - dy);
                float wd = dx * dy;
                float Ia, Ib, Ic, Id;
                if ((okm >> k) & 1) {
                    int t = li[k];
                    Ia = tile[t];        Ic = tile[t + 1];
                    Ib = tile[t + LWP];  Id = tile[t + LWP + 1];
                } else {
                    int g = li[k];
                    Ia = gimg[g];        Ic = gimg[g + 1];
                    Ib = gimg[g + W];    Id = gimg[g + W + 1];
                }
                __builtin_nontemporal_store(
                    wa * Ia + wb * Ib + wc * Ic + wd * Id, outc + k * W);
            }
        }
    }
}

extern "C" void kernel_launch(void* const* d_in, const int* in_sizes, int n_in,
                              void* d_out, int out_size, void* d_ws, size_t ws_size,
                              hipStream_t stream) {
    const float* images = (const float*)d_in[0];
    const float* flows  = (const float*)d_in[1];
    float* out = (float*)d_out;

    dim3 block(1024);
    dim3 grid(TILES);                     // 1024 blocks
    hipLaunchKernelGGL(warp_bilinear_rows, grid, block, 0, stream,
                       images, flows, out);
}

// Round 10
// 45.812 us; speedup vs baseline: 1.3807x; 1.3807x over previous
//
#include <hip/hip_runtime.h>

// Bilinear flow warp, LDS row-tile v6b: counted-vmcnt pipelined channels.
// images [32,3,512,512] f32, flows [32,2,512,512] f32 (ch0=dy, ch1=dx).
//
// R9 post-mortem: vmcnt(24) was a NO-OP -- vmcnt counts WAVE-level VMEM
// instructions (4 stage global_load_lds + 8 nt stores per channel), not
// per-thread elements. The barrier stopped guaranteeing stage completion ->
// race -> absmax 0.91. Fix: vmcnt(8). In-order retirement (m135) means
// vmcnt(8) drains the 4 stage loads (oldest, plus any leftover prior-channel
// stores) while this channel's 8 stores (newest) stay in flight. Slow path
// always issues >=8 VMEM ops after the stage loads, so the bound holds there
// too. lgkmcnt(0) before s_barrier preserves the buffer-reuse hazard proof.

constexpr int C = 3, H = 512, W = 512, HW = H * W;
constexpr int TH = 8, HALO = 4;
constexpr int LROWS = TH + 2 * HALO;      // 16 staged rows
constexpr int LWP   = W;                  // 512: stride == 0 mod 32 banks
constexpr int TILES = 32 * (H / TH);      // 2048 blocks, %8 == 0

__global__ __launch_bounds__(512) void warp_bilinear_rows(
    const float* __restrict__ images,
    const float* __restrict__ flows,
    float* __restrict__ out)
{
    __shared__ float tile[2][LROWS * LWP];   // 2 x 32,768 B

    // XCD-contiguous: XCD r owns tiles [r*256,(r+1)*256) = 4 whole batches.
    int bid = blockIdx.x;
    int tile_id = (bid & 7) * (TILES / 8) + (bid >> 3);
    int b   = tile_id >> 6;               // 64 row-tiles per batch
    int ty0 = (tile_id & 63) * TH;

    int tid = threadIdx.x;                // 0..511 = my column

    // ---- flow load + channel-independent gather state (8 px/thread) ----
    const float* flow_y = flows + (size_t)b * 2 * HW + ty0 * W + tid;
    const float* flow_x = flow_y + HW;

    float dxv[TH], dyv[TH];
    int   li[TH];
    unsigned okm = 0;
#pragma unroll
    for (int k = 0; k < TH; ++k) {
        float fy = flow_y[k * W];
        float fx = flow_x[k * W];
        float sx = fminf(fmaxf((float)tid + fx, 0.0f), (float)(W - 1));
        float sy = fminf(fmaxf((float)(ty0 + k) + fy, 0.0f), (float)(H - 1));
        int x0 = min((int)sx, W - 2);     // sx >= 0 so (int) == floor
        int y0 = min((int)sy, H - 2);
        dxv[k] = sx - (float)x0;
        dyv[k] = sy - (float)y0;
        int ly0 = y0 - (ty0 - HALO);
        bool ok = (ly0 >= 0) & (ly0 <= LROWS - 2);
        okm |= (unsigned)ok << k;
        li[k] = ok ? (ly0 * LWP + x0)     // LDS offset (x needs no halo)
                   : (y0 * W + x0);       // global fallback offset
    }
    bool fast = __all(okm == ((1u << TH) - 1));

    // staging addresses (channel-invariant): wave-uniform row + lane*16B
    int srow[LROWS / 4];
    int scol = (tid & 127) * 4;
#pragma unroll
    for (int it = 0; it < LROWS / 4; ++it) {
        int r = it * 4 + (tid >> 7);
        srow[it] = min(max(ty0 - HALO + r, 0), H - 1);
    }

    auto stage = [&](int c, int buf) {
        const float* gimg = images + ((size_t)b * C + c) * HW;
#pragma unroll
        for (int it = 0; it < LROWS / 4; ++it) {    // 4 wave-level loads
            int r = it * 4 + (tid >> 7);
            __builtin_amdgcn_global_load_lds(
                (const __attribute__((address_space(1))) void*)(gimg + srow[it] * W + scol),
                (__attribute__((address_space(3))) void*)(&tile[buf][r * LWP + scol]),
                16, 0, 0);
        }
    };

    stage(0, 0);
    __syncthreads();                      // cold drain (only full one)

#pragma unroll
    for (int c = 0; c < C; ++c) {
        if (c + 1 < C) stage(c + 1, (c + 1) & 1);   // issue-early prefetch
        __builtin_amdgcn_sched_barrier(0);          // pin: stage before gather

        const float* gimg = images + ((size_t)b * C + c) * HW;  // fallback
        const float* tb = tile[c & 1];
        float* outc = out + ((size_t)b * C + c) * HW + ty0 * W + tid;

        if (fast) {
#pragma unroll
            for (int k = 0; k < TH; ++k) {
                float dx = dxv[k], dy = dyv[k];
                float wa = (1.0f - dx) * (1.0f - dy);
                float wb = (1.0f - dx) * dy;
                float wc = dx * (1.0f - dy);
                float wd = dx * dy;
                int t = li[k];
                float Ia = tb[t];        float Ic = tb[t + 1];
                float Ib = tb[t + LWP];  float Id = tb[t + LWP + 1];
                __builtin_nontemporal_store(
                    wa * Ia + wb * Ib + wc * Ic + wd * Id, outc + k * W);
            }
        } else {                           // rare: |dy| > ~4 near strip edge
#pragma unroll
            for (int k = 0; k < TH; ++k) {
                float dx = dxv[k], dy = dyv[k];
                float wa = (1.0f - dx) * (1.0f - dy);
                float wb = (1.0f - dx) * dy;
                float wc = dx * (1.0f - dy);
                float wd = dx * dy;
                float Ia, Ib, Ic, Id;
                if ((okm >> k) & 1) {
                    int t = li[k];
                    Ia = tb[t];        Ic = tb[t + 1];
                    Ib = tb[t + LWP];  Id = tb[t + LWP + 1];
                } else {
                    int g = li[k];
                    Ia = gimg[g];        Ic = gimg[g + 1];
                    Ib = gimg[g + W];    Id = gimg[g + W + 1];
                }
                __builtin_nontemporal_store(
                    wa * Ia + wb * Ib + wc * Ic + wd * Id, outc + k * W);
            }
        }

        if (c + 1 < C) {
            // Drain my ds_reads (lgkm) and everything except the 8 newest
            // VMEM ops (= this channel's nt stores): the 4 prefetch loads
            // are strictly older, so they are guaranteed landed. Then raw
            // barrier -> all waves' next buffer is consistent.
            asm volatile("s_waitcnt vmcnt(8) lgkmcnt(0)" ::: "memory");
            __builtin_amdgcn_sched_barrier(0);
            __builtin_amdgcn_s_barrier();
            __builtin_amdgcn_sched_barrier(0);
        }
    }
}

extern "C" void kernel_launch(void* const* d_in, const int* in_sizes, int n_in,
                              void* d_out, int out_size, void* d_ws, size_t ws_size,
                              hipStream_t stream) {
    const float* images = (const float*)d_in[0];
    const float* flows  = (const float*)d_in[1];
    float* out = (float*)d_out;

    dim3 block(512);
    dim3 grid(TILES);                     // 2048 blocks
    hipLaunchKernelGGL(warp_bilinear_rows, grid, block, 0, stream,
                       images, flows, out);
}